// Round 2
// baseline (20436.919 us; speedup 1.0000x reference)
//
#include <hip/hip_runtime.h>

#define NBLK 256

typedef short bf16x8 __attribute__((ext_vector_type(8)));
typedef float f32x4 __attribute__((ext_vector_type(4)));

static __device__ __forceinline__ unsigned short f2b(float x){
  union { float f; unsigned u; } v; v.f = x;
  unsigned r = v.u + 0x7fffu + ((v.u >> 16) & 1u);
  return (unsigned short)(r >> 16);
}
static __device__ __forceinline__ float sigmoidf_(float x){
  return 1.0f / (1.0f + __expf(-x));
}
static __device__ __forceinline__ float tanhf_(float x){
  float e2 = __expf(-2.0f * fabsf(x));
  float t = (1.0f - e2) / (1.0f + e2);
  return x < 0.0f ? -t : t;
}

// ---------------- device-scope grid barrier (gen-counter) ----------------
static __device__ __forceinline__ void gbar(unsigned* cnt, unsigned* gen){
  __syncthreads();
  __threadfence();
  if (threadIdx.x == 0){
    unsigned g = __hip_atomic_load(gen, __ATOMIC_ACQUIRE, __HIP_MEMORY_SCOPE_AGENT);
    unsigned a = __hip_atomic_fetch_add(cnt, 1u, __ATOMIC_ACQ_REL, __HIP_MEMORY_SCOPE_AGENT);
    if (a == NBLK - 1u){
      __hip_atomic_store(cnt, 0u, __ATOMIC_RELAXED, __HIP_MEMORY_SCOPE_AGENT);
      __hip_atomic_fetch_add(gen, 1u, __ATOMIC_RELEASE, __HIP_MEMORY_SCOPE_AGENT);
    } else {
      while (__hip_atomic_load(gen, __ATOMIC_ACQUIRE, __HIP_MEMORY_SCOPE_AGENT) == g){
        __builtin_amdgcn_s_sleep(2);
      }
    }
  }
  __threadfence();
  __syncthreads();
}

// ---------------- generic 64x64 MFMA tile: C = A @ W^T (+bias) ----------------
// A: M x K (f32 or bf16), W: N x K bf16. mode 0: f32 (ldc); 1: bf16; 2: relu+bf16;
// mode 3: f32 with encoder (b,t) row remap into out[b][t][64]
static __device__ void gemm_tile(const void* __restrict__ Aptr, int a_is_f32,
                                 const unsigned short* __restrict__ W,
                                 const float* __restrict__ bias,
                                 void* __restrict__ Cptr, int mode,
                                 int K, int ldc, int bx, int by)
{
  const int lane = threadIdx.x & 63;
  const int wave = threadIdx.x >> 6;
  const int ln = lane & 15;
  const int kq = lane >> 4;
  const int m0 = by * 64 + wave * 16;
  const int n0 = bx * 64;

  f32x4 acc[4] = {};
  const int arow = m0 + ln;
  const unsigned short* wp = W + (size_t)(n0 + ln) * K + kq * 8;
  const int nk = K >> 5;

  if (a_is_f32){
    const float* ap = (const float*)Aptr + (size_t)arow * K + kq * 8;
    for (int t = 0; t < nk; ++t){
      f32x4 u0 = *(const f32x4*)(ap);
      f32x4 u1 = *(const f32x4*)(ap + 4);
      bf16x8 af;
      af[0] = (short)f2b(u0[0]); af[1] = (short)f2b(u0[1]);
      af[2] = (short)f2b(u0[2]); af[3] = (short)f2b(u0[3]);
      af[4] = (short)f2b(u1[0]); af[5] = (short)f2b(u1[1]);
      af[6] = (short)f2b(u1[2]); af[7] = (short)f2b(u1[3]);
      #pragma unroll
      for (int j = 0; j < 4; j++){
        bf16x8 wf = *(const bf16x8*)(wp + (size_t)(16 * j) * K);
        acc[j] = __builtin_amdgcn_mfma_f32_16x16x32_bf16(af, wf, acc[j], 0, 0, 0);
      }
      ap += 32; wp += 32;
    }
  } else {
    const unsigned short* ap = (const unsigned short*)Aptr + (size_t)arow * K + kq * 8;
    for (int t = 0; t < nk; ++t){
      bf16x8 af = *(const bf16x8*)ap;
      #pragma unroll
      for (int j = 0; j < 4; j++){
        bf16x8 wf = *(const bf16x8*)(wp + (size_t)(16 * j) * K);
        acc[j] = __builtin_amdgcn_mfma_f32_16x16x32_bf16(af, wf, acc[j], 0, 0, 0);
      }
      ap += 32; wp += 32;
    }
  }

  #pragma unroll
  for (int j = 0; j < 4; j++){
    int col = n0 + 16 * j + ln;
    float bv = bias ? bias[col] : 0.0f;
    #pragma unroll
    for (int r = 0; r < 4; r++){
      int orow = m0 + kq * 4 + r;
      float v = acc[j][r] + bv;
      if (mode == 0){
        ((float*)Cptr)[(size_t)orow * ldc + col] = v;
      } else if (mode == 1){
        ((unsigned short*)Cptr)[(size_t)orow * ldc + col] = f2b(v);
      } else if (mode == 2){
        ((unsigned short*)Cptr)[(size_t)orow * ldc + col] = f2b(v > 0.f ? v : 0.f);
      } else {
        int bb = orow / 140;
        int tt = orow - bb * 140;
        ((float*)Cptr)[((size_t)bb * 280 + tt) * 64 + col] = v;
      }
    }
  }
}

// ---------------- fused elementwise prologue ----------------
__global__ __launch_bounds__(256)
void k_prep(const float* __restrict__ enc, const float* __restrict__ ehid,
            const float* __restrict__ embW, const float* __restrict__ emb_b,
            const float* __restrict__ w_ih, const float* __restrict__ w_hh,
            const float* __restrict__ b_hh,
            const float* __restrict__ out_W, const float* __restrict__ out_b,
            const float* __restrict__ reg_W, const float* __restrict__ reg_b,
            unsigned short* __restrict__ wih16, unsigned short* __restrict__ Wbig,
            unsigned short* __restrict__ embW16, unsigned short* __restrict__ regW16,
            unsigned short* __restrict__ outWT16, float* __restrict__ bias_big,
            unsigned short* __restrict__ h16, unsigned short* __restrict__ x016,
            unsigned* __restrict__ bar)
{
  int b = blockIdx.x, t = threadIdx.x;
  if (b < 3072){ int i = b * 256 + t; wih16[i] = f2b(w_ih[i]); }
  else if (b < 6144){ int i = (b - 3072) * 256 + t; Wbig[(size_t)512 * 512 + i] = f2b(w_hh[i]); }
  else if (b < 6656){ int i = (b - 6144) * 256 + t; embW16[i] = f2b(embW[i]); }
  else if (b < 6720){ int i = (b - 6656) * 256 + t; regW16[i] = f2b(reg_W[i]); }
  else if (b < 7232){ int i = (b - 6720) * 256 + t; int j = i >> 8, k = i & 255;
                      outWT16[i] = f2b(out_W[k * 512 + j]); }
  else if (b < 7241){
    int i = (b - 7232) * 256 + t;
    if (i < 512){
      float s = emb_b[i];
      for (int k = 0; k < 256; k++) s += embW[i * 256 + k] * out_b[k];
      bias_big[i] = s;
    } else if (i < 2048){
      bias_big[i] = b_hh[i - 512];
    } else if (i < 2112){
      int o = i - 2048;
      float s = reg_b[o];
      for (int k = 0; k < 256; k++) s += reg_W[o * 256 + k] * out_b[k];
      bias_big[i] = s;
    }
  }
  else if (b < 8265){ int i = (b - 7241) * 256 + t; h16[i] = f2b(ehid[i]); }
  else if (b < 8777){ int i = (b - 8265) * 256 + t; int bb = i >> 8, k = i & 255;
                      x016[i] = f2b(enc[((size_t)bb * 140 + 139) * 256 + k]); }
  else { if (t < 64) bar[t] = 0u; }
}

// ---------------- all independent prologue GEMMs in one launch ----------------
__global__ __launch_bounds__(256)
void k_gemms(const float* __restrict__ enc, const float* __restrict__ embW,
             const float* __restrict__ emb_b, const float* __restrict__ b_hh,
             const float* __restrict__ reg_W, const float* __restrict__ reg_b,
             const unsigned short* __restrict__ embW16, const unsigned short* __restrict__ regW16,
             const unsigned short* __restrict__ outWT16, const unsigned short* __restrict__ x016,
             const unsigned short* __restrict__ h16,
             unsigned short* __restrict__ Wbig, unsigned short* __restrict__ e16,
             float* __restrict__ gh, float* __restrict__ out)
{
  int b = blockIdx.x;
  if (b < 64){                       // W_comb = emb_W @ out_W -> Wbig rows [0,512)
    gemm_tile(embW, 1, outWT16, nullptr, Wbig, 1, 256, 512, b & 7, b >> 3);
  } else if (b < 72){                // W_or = reg_W @ out_W -> Wbig rows [2048,2112)
    gemm_tile(reg_W, 1, outWT16, nullptr, Wbig + (size_t)2048 * 512, 1, 256, 512, b - 64, 0);
  } else if (b < 136){               // e0 = relu(x0 @ emb_W^T + emb_b)
    int c = b - 72;
    gemm_tile(x016, 0, embW16, emb_b, e16, 2, 256, 512, c & 7, c >> 3);
  } else if (b < 328){               // gh0 = h0 @ w_hh^T + b_hh
    int c = b - 136;
    gemm_tile(h16, 0, Wbig + (size_t)512 * 512, b_hh, gh, 0, 512, 1536, c % 24, c / 24);
  } else {                           // encoder projection -> out[:, 0:140, :]
    int c = b - 328;
    gemm_tile(enc, 1, regW16, reg_b, out, 3, 256, 0, 0, c);
  }
}

// ---------------- persistent GRU loop ----------------
__global__ __launch_bounds__(256)
void k_loop(const float* __restrict__ ehid,
            const unsigned short* __restrict__ wih16,
            const float* __restrict__ b_ih,
            const unsigned short* __restrict__ Wbig,
            const float* __restrict__ bias_big,
            unsigned short* __restrict__ e16,
            float* __restrict__ gh,
            unsigned short* __restrict__ h16,
            float* __restrict__ out,
            unsigned* __restrict__ bar)
{
  const int blk = blockIdx.x;
  const int lane = threadIdx.x & 63;
  const int wave = threadIdx.x >> 6;
  const int ln = lane & 15;
  const int kq = lane >> 4;

  // P2 tile (fixed across steps): 64 rows x 16 j-cols x 3 gates
  const int m0p2 = (blk & 7) * 64 + wave * 16;
  const int j0 = (blk >> 3) * 16;
  const int j = j0 + ln;
  const float bR = b_ih[j], bZ = b_ih[512 + j], bN = b_ih[1024 + j];

  // h lives in registers: this thread owns rows m0p2+kq*4+r at col j forever
  float hreg[4];
  #pragma unroll
  for (int r = 0; r < 4; r++) hreg[r] = ehid[(size_t)(m0p2 + kq * 4 + r) * 512 + j];

  // P1 tile: 176 active blocks, 64 rows x 96 cols of the 512x2112 output
  const int n0 = (blk >> 3) * 96;
  const int m0p1 = (blk & 7) * 64 + wave * 16;
  const bool p1act = (blk < 176);

  unsigned* cnt = bar;
  unsigned* gen = bar + 32;

  for (int s = 0; s < 140; ++s){
    // ---- P2: gi = e @ w_ih^T, GRU gates -> h (regs), h16 ----
    {
      f32x4 aR = {}, aZ = {}, aN = {};
      const unsigned short* ap  = e16 + (size_t)(m0p2 + ln) * 512 + kq * 8;
      const unsigned short* wpR = wih16 + (size_t)(j0 + ln) * 512 + kq * 8;
      const unsigned short* wpZ = wpR + (size_t)512 * 512;
      const unsigned short* wpN = wpR + (size_t)1024 * 512;
      for (int t = 0; t < 16; ++t){
        bf16x8 af = *(const bf16x8*)ap;
        aR = __builtin_amdgcn_mfma_f32_16x16x32_bf16(af, *(const bf16x8*)wpR, aR, 0, 0, 0);
        aZ = __builtin_amdgcn_mfma_f32_16x16x32_bf16(af, *(const bf16x8*)wpZ, aZ, 0, 0, 0);
        aN = __builtin_amdgcn_mfma_f32_16x16x32_bf16(af, *(const bf16x8*)wpN, aN, 0, 0, 0);
        ap += 32; wpR += 32; wpZ += 32; wpN += 32;
      }
      #pragma unroll
      for (int r = 0; r < 4; r++){
        int b = m0p2 + kq * 4 + r;
        const float* g = gh + (size_t)b * 1536;
        float rg = sigmoidf_(aR[r] + bR + g[j]);
        float z  = sigmoidf_(aZ[r] + bZ + g[512 + j]);
        float nn = tanhf_(aN[r] + bN + rg * g[1024 + j]);
        float hv = (1.f - z) * nn + z * hreg[r];
        hreg[r] = hv;
        h16[(size_t)b * 512 + j] = f2b(hv);
      }
    }
    gbar(cnt, gen);

    // ---- P1: T = h16 @ Wbig^T + bias -> e16 | gh | y_s ----
    if (p1act){
      f32x4 acc[6] = {};
      const unsigned short* ap = h16 + (size_t)(m0p1 + ln) * 512 + kq * 8;
      const unsigned short* wp = Wbig + (size_t)(n0 + ln) * 512 + kq * 8;
      for (int t = 0; t < 16; ++t){
        bf16x8 af = *(const bf16x8*)ap;
        #pragma unroll
        for (int jj = 0; jj < 6; jj++){
          bf16x8 wf = *(const bf16x8*)(wp + (size_t)(16 * jj) * 512);
          acc[jj] = __builtin_amdgcn_mfma_f32_16x16x32_bf16(af, wf, acc[jj], 0, 0, 0);
        }
        ap += 32; wp += 32;
      }
      #pragma unroll
      for (int jj = 0; jj < 6; jj++){
        int col = n0 + 16 * jj + ln;
        float bv = bias_big[col];
        #pragma unroll
        for (int r = 0; r < 4; r++){
          int b = m0p1 + kq * 4 + r;
          float v = acc[jj][r] + bv;
          if (col < 512){
            e16[(size_t)b * 512 + col] = f2b(v > 0.f ? v : 0.f);
          } else if (col < 2048){
            gh[(size_t)b * 1536 + (col - 512)] = v;
          } else {
            out[((size_t)b * 280 + 140 + s) * 64 + (col - 2048)] = v;
          }
        }
      }
    }
    if (s != 139) gbar(cnt, gen);
  }
}

extern "C" void kernel_launch(void* const* d_in, const int* in_sizes, int n_in,
                              void* d_out, int out_size, void* d_ws, size_t ws_size,
                              hipStream_t stream)
{
  const float* enc   = (const float*)d_in[0];
  const float* ehid  = (const float*)d_in[1];
  const float* embW  = (const float*)d_in[2];
  const float* emb_b = (const float*)d_in[3];
  const float* w_ih  = (const float*)d_in[4];
  const float* w_hh  = (const float*)d_in[5];
  const float* b_ih  = (const float*)d_in[6];
  const float* b_hh  = (const float*)d_in[7];
  const float* out_W = (const float*)d_in[8];
  const float* out_b = (const float*)d_in[9];
  const float* reg_W = (const float*)d_in[10];
  const float* reg_b = (const float*)d_in[11];
  float* out = (float*)d_out;

  char* ws = (char*)d_ws;
  size_t off = 0;
  auto alloc = [&](size_t bytes)->char*{
    char* p = ws + off; off += (bytes + 255) & ~(size_t)255; return p;
  };
  unsigned short* Wbig    = (unsigned short*)alloc((size_t)2112 * 512 * 2);
  unsigned short* wih16   = (unsigned short*)alloc((size_t)1536 * 512 * 2);
  unsigned short* embW16  = (unsigned short*)alloc((size_t)512 * 256 * 2);
  unsigned short* regW16  = (unsigned short*)alloc((size_t)64 * 256 * 2);
  unsigned short* outWT16 = (unsigned short*)alloc((size_t)512 * 256 * 2);
  float*          bias_big= (float*)alloc((size_t)2112 * 4);
  unsigned short* e16     = (unsigned short*)alloc((size_t)512 * 512 * 2);
  float*          gh      = (float*)alloc((size_t)512 * 1536 * 4);
  unsigned short* h16     = (unsigned short*)alloc((size_t)512 * 512 * 2);
  unsigned short* x016    = (unsigned short*)alloc((size_t)512 * 256 * 2);
  unsigned*       bar     = (unsigned*)alloc(256);

  k_prep<<<8778, 256, 0, stream>>>(enc, ehid, embW, emb_b, w_ih, w_hh, b_hh,
                                   out_W, out_b, reg_W, reg_b,
                                   wih16, Wbig, embW16, regW16, outWT16, bias_big,
                                   h16, x016, bar);

  k_gemms<<<1448, 256, 0, stream>>>(enc, embW, emb_b, b_hh, reg_W, reg_b,
                                    embW16, regW16, outWT16, x016, h16,
                                    Wbig, e16, gh, out);

  k_loop<<<NBLK, 256, 0, stream>>>(ehid, wih16, b_ih, Wbig, bias_big,
                                   e16, gh, h16, out, bar);
}

// Round 3
// 14062.384 us; speedup vs baseline: 1.4533x; 1.4533x over previous
//
#include <hip/hip_runtime.h>

#define PAD 520   // LDS row stride (elements) for 512-wide rows: +8 elems = +4 banks
#define XPAD 264  // LDS row stride for 256-wide x0 rows

typedef short bf16x8 __attribute__((ext_vector_type(8)));
typedef float f32x4 __attribute__((ext_vector_type(4)));

static __device__ __forceinline__ unsigned short f2b(float x){
  union { float f; unsigned u; } v; v.f = x;
  unsigned r = v.u + 0x7fffu + ((v.u >> 16) & 1u);
  return (unsigned short)(r >> 16);
}
static __device__ __forceinline__ float sigmoidf_(float x){
  return 1.0f / (1.0f + __expf(-x));
}
static __device__ __forceinline__ float tanhf_(float x){
  float e2 = __expf(-2.0f * fabsf(x));
  float t = (1.0f - e2) / (1.0f + e2);
  return x < 0.0f ? -t : t;
}
static __device__ __forceinline__ bf16x8 pack8(f32x4 u0, f32x4 u1){
  bf16x8 a;
  a[0] = (short)f2b(u0[0]); a[1] = (short)f2b(u0[1]);
  a[2] = (short)f2b(u0[2]); a[3] = (short)f2b(u0[3]);
  a[4] = (short)f2b(u1[0]); a[5] = (short)f2b(u1[1]);
  a[6] = (short)f2b(u1[2]); a[7] = (short)f2b(u1[3]);
  return a;
}

// ---------------- elementwise prologue: casts + fused biases ----------------
__global__ __launch_bounds__(256)
void k_prep(const float* __restrict__ embW, const float* __restrict__ emb_b,
            const float* __restrict__ w_ih, const float* __restrict__ w_hh,
            const float* __restrict__ b_hh,
            const float* __restrict__ out_W, const float* __restrict__ out_b,
            const float* __restrict__ reg_W, const float* __restrict__ reg_b,
            unsigned short* __restrict__ wih16, unsigned short* __restrict__ Wbig,
            unsigned short* __restrict__ embW16, unsigned short* __restrict__ regW16,
            unsigned short* __restrict__ outWT16, float* __restrict__ bias_big)
{
  int b = blockIdx.x, t = threadIdx.x;
  if (b < 3072){ int i = b * 256 + t; wih16[i] = f2b(w_ih[i]); }
  else if (b < 6144){ int i = (b - 3072) * 256 + t; Wbig[(size_t)512 * 512 + i] = f2b(w_hh[i]); }
  else if (b < 6656){ int i = (b - 6144) * 256 + t; embW16[i] = f2b(embW[i]); }
  else if (b < 6720){ int i = (b - 6656) * 256 + t; regW16[i] = f2b(reg_W[i]); }
  else if (b < 7232){ int i = (b - 6720) * 256 + t; int j = i >> 8, k = i & 255;
                      outWT16[i] = f2b(out_W[k * 512 + j]); }
  else {
    int i = (b - 7232) * 256 + t;
    if (i < 512){
      float s = emb_b[i];
      for (int k = 0; k < 256; k++) s += embW[i * 256 + k] * out_b[k];
      bias_big[i] = s;
    } else if (i < 2048){
      bias_big[i] = b_hh[i - 512];
    } else if (i < 2112){
      int o = i - 2048;
      float s = reg_b[o];
      for (int k = 0; k < 256; k++) s += reg_W[o * 256 + k] * out_b[k];
      bias_big[i] = s;
    }
  }
}

// ---------------- weight-fold GEMMs: C(bf16) = A(f32) @ W(bf16)^T ----------------
static __device__ void fold_tile(const float* __restrict__ A,
                                 const unsigned short* __restrict__ W,
                                 unsigned short* __restrict__ C,
                                 int K, int ldc, int bx, int by)
{
  const int lane = threadIdx.x & 63;
  const int wave = threadIdx.x >> 6;
  const int ln = lane & 15;
  const int kq = lane >> 4;
  const int m0 = by * 64 + wave * 16;
  const int n0 = bx * 64;
  f32x4 acc[4] = {};
  const float* ap = A + (size_t)(m0 + ln) * K + kq * 8;
  const unsigned short* wp = W + (size_t)(n0 + ln) * K + kq * 8;
  for (int t = 0; t < (K >> 5); ++t){
    f32x4 u0 = *(const f32x4*)(ap);
    f32x4 u1 = *(const f32x4*)(ap + 4);
    bf16x8 af = pack8(u0, u1);
    #pragma unroll
    for (int j = 0; j < 4; j++){
      bf16x8 wf = *(const bf16x8*)(wp + (size_t)(16 * j) * K);
      acc[j] = __builtin_amdgcn_mfma_f32_16x16x32_bf16(af, wf, acc[j], 0, 0, 0);
    }
    ap += 32; wp += 32;
  }
  #pragma unroll
  for (int j = 0; j < 4; j++){
    int col = n0 + 16 * j + ln;
    #pragma unroll
    for (int r = 0; r < 4; r++){
      int orow = m0 + kq * 4 + r;
      C[(size_t)orow * ldc + col] = f2b(acc[j][r]);
    }
  }
}

__global__ __launch_bounds__(256)
void k_gemms(const float* __restrict__ embW, const float* __restrict__ reg_W,
             const unsigned short* __restrict__ outWT16,
             unsigned short* __restrict__ Wbig)
{
  int b = blockIdx.x;
  if (b < 64){        // Wc = emb_W @ out_W -> Wbig rows [0,512)
    fold_tile(embW, outWT16, Wbig, 256, 512, b & 7, b >> 3);
  } else {            // W_or = reg_W @ out_W -> Wbig rows [2048,2112)
    fold_tile(reg_W, outWT16, Wbig + (size_t)2048 * 512, 256, 512, b - 64, 0);
  }
}

// ---------------- main kernel: 32 block-local GRU streams + encoder proj ----------------
__global__ __launch_bounds__(512, 2)
void k_loop(const float* __restrict__ enc, const float* __restrict__ ehid,
            const float* __restrict__ emb_b, const float* __restrict__ b_ih,
            const float* __restrict__ b_hh,
            const unsigned short* __restrict__ wih16,
            const unsigned short* __restrict__ Wbig,
            const unsigned short* __restrict__ embW16,
            const unsigned short* __restrict__ regW16,
            const float* __restrict__ bias_big, const float* __restrict__ reg_b,
            float* __restrict__ out)
{
  __shared__ __attribute__((aligned(16))) unsigned short h16[16 * PAD];
  __shared__ __attribute__((aligned(16))) unsigned short e16[16 * PAD];
  __shared__ __attribute__((aligned(16))) unsigned short x0s[16 * XPAD];

  const int blk = blockIdx.x;
  const int tid = threadIdx.x;
  const int w = tid >> 6;
  const int lane = tid & 63;
  const int ln = lane & 15;
  const int kq = lane >> 4;

  if (blk >= 32){
    // -------- encoder projection: out[:, 0:140, :] = enc @ reg_W^T + reg_b --------
    for (int t = blk - 32; t < 560; t += 224){
      const int m0 = t * 128 + w * 16;
      f32x4 acc[4] = {};
      const float* ap = enc + (size_t)(m0 + ln) * 256 + kq * 8;
      const unsigned short* bp = regW16 + (size_t)ln * 256 + kq * 8;
      for (int k = 0; k < 8; ++k){
        f32x4 u0 = *(const f32x4*)(ap);
        f32x4 u1 = *(const f32x4*)(ap + 4);
        bf16x8 af = pack8(u0, u1);
        #pragma unroll
        for (int c = 0; c < 4; ++c){
          bf16x8 wf = *(const bf16x8*)(bp + (size_t)(16 * c) * 256);
          acc[c] = __builtin_amdgcn_mfma_f32_16x16x32_bf16(af, wf, acc[c], 0, 0, 0);
        }
        ap += 32; bp += 32;
      }
      #pragma unroll
      for (int c = 0; c < 4; ++c){
        int col = c * 16 + ln;
        float bv = reg_b[col];
        #pragma unroll
        for (int r = 0; r < 4; ++r){
          int orow = m0 + kq * 4 + r;
          int bb = orow / 140, tt = orow - bb * 140;
          out[((size_t)bb * 280 + tt) * 64 + col] = acc[c][r] + bv;
        }
      }
    }
    return;
  }

  // -------- recurrence for batch rows [g0, g0+16) --------
  const int g0 = blk * 16;
  const int lrow = kq * 4;        // this lane's first local row

  // persistent h in registers: hreg[q][r] = h[lrow+r][ (4w+q)*16+ln ]
  float hreg[4][4];
  #pragma unroll
  for (int q = 0; q < 4; q++){
    int j = (w * 4 + q) * 16 + ln;
    #pragma unroll
    for (int r = 0; r < 4; r++)
      hreg[q][r] = ehid[(size_t)(g0 + lrow + r) * 512 + j];
  }
  // stage h16 and x0
  #pragma unroll
  for (int q = 0; q < 4; q++){
    int j = (w * 4 + q) * 16 + ln;
    #pragma unroll
    for (int r = 0; r < 4; r++)
      h16[(lrow + r) * PAD + j] = f2b(hreg[q][r]);
  }
  for (int i = tid; i < 16 * 256; i += 512){
    int rr = i >> 8, cc = i & 255;
    x0s[rr * XPAD + cc] = f2b(enc[((size_t)(g0 + rr) * 140 + 139) * 256 + cc]);
  }
  __syncthreads();

  // per-thread biases
  float brz0[4], brz1[4], bin_[4], bhn_[4], eb0[4], ebig[4];
  #pragma unroll
  for (int q = 0; q < 4; q++){
    int j = (w * 4 + q) * 16 + ln;
    brz0[q] = b_ih[j] + b_hh[j];
    brz1[q] = b_ih[512 + j] + b_hh[512 + j];
    bin_[q] = b_ih[1024 + j];
    bhn_[q] = b_hh[1024 + j];
    eb0[q]  = emb_b[j];
    ebig[q] = bias_big[j];
  }
  const float yb = (w < 4) ? bias_big[2048 + w * 16 + ln] : 0.f;

  // accumulators carried P1 -> P2 (gh fused as MFMA C for r,z; separate for n)
  f32x4 aRZ0[4], aRZ1[4], aN[4];

  // gh part of P1 from current h16 (zero-init, accumulate over K=512)
  auto p1_gh = [&](){
    #pragma unroll
    for (int q = 0; q < 4; q++){ aRZ0[q] = (f32x4){}; aRZ1[q] = (f32x4){}; aN[q] = (f32x4){}; }
    const unsigned short* a0 = h16 + ln * PAD + kq * 8;
    #pragma unroll 2
    for (int k = 0; k < 16; ++k){
      bf16x8 af = *(const bf16x8*)(a0 + k * 32);
      #pragma unroll
      for (int q = 0; q < 4; q++){
        int jt = w * 4 + q;
        const unsigned short* br = Wbig + (size_t)(512  + jt * 16 + ln) * 512 + k * 32 + kq * 8;
        const unsigned short* bz = Wbig + (size_t)(1024 + jt * 16 + ln) * 512 + k * 32 + kq * 8;
        const unsigned short* bn = Wbig + (size_t)(1536 + jt * 16 + ln) * 512 + k * 32 + kq * 8;
        aRZ0[q] = __builtin_amdgcn_mfma_f32_16x16x32_bf16(af, *(const bf16x8*)br, aRZ0[q], 0, 0, 0);
        aRZ1[q] = __builtin_amdgcn_mfma_f32_16x16x32_bf16(af, *(const bf16x8*)bz, aRZ1[q], 0, 0, 0);
        aN[q]   = __builtin_amdgcn_mfma_f32_16x16x32_bf16(af, *(const bf16x8*)bn, aN[q],   0, 0, 0);
      }
    }
  };

  // ---- e0 = relu(x0 @ embW^T + emb_b) ----
  {
    f32x4 acce[4] = {};
    const unsigned short* a0 = x0s + ln * XPAD + kq * 8;
    #pragma unroll 2
    for (int k = 0; k < 8; ++k){
      bf16x8 af = *(const bf16x8*)(a0 + k * 32);
      #pragma unroll
      for (int q = 0; q < 4; q++){
        const unsigned short* bp = embW16 + (size_t)((w * 4 + q) * 16 + ln) * 256 + k * 32 + kq * 8;
        acce[q] = __builtin_amdgcn_mfma_f32_16x16x32_bf16(af, *(const bf16x8*)bp, acce[q], 0, 0, 0);
      }
    }
    #pragma unroll
    for (int q = 0; q < 4; q++){
      int j = (w * 4 + q) * 16 + ln;
      #pragma unroll
      for (int r = 0; r < 4; r++){
        float v = acce[q][r] + eb0[q];
        e16[(lrow + r) * PAD + j] = f2b(v > 0.f ? v : 0.f);
      }
    }
  }
  // ---- gh0 ----
  p1_gh();
  __syncthreads();

  // ---- 140 steps ----
  for (int s = 0; s < 140; ++s){
    // P2: gi = e @ w_ih^T (accumulated onto gh for r,z), gates, h update
    #pragma unroll
    for (int q = 0; q < 4; q++){
      int jt = w * 4 + q;
      f32x4 accN = {};
      const unsigned short* a0 = e16 + ln * PAD + kq * 8;
      const unsigned short* br = wih16 + (size_t)(jt * 16 + ln) * 512 + kq * 8;
      const unsigned short* bz = br + (size_t)512 * 512;
      const unsigned short* bn = br + (size_t)1024 * 512;
      #pragma unroll 2
      for (int k = 0; k < 16; ++k){
        bf16x8 af = *(const bf16x8*)(a0 + k * 32);
        aRZ0[q] = __builtin_amdgcn_mfma_f32_16x16x32_bf16(af, *(const bf16x8*)(br + k * 32), aRZ0[q], 0, 0, 0);
        aRZ1[q] = __builtin_amdgcn_mfma_f32_16x16x32_bf16(af, *(const bf16x8*)(bz + k * 32), aRZ1[q], 0, 0, 0);
        accN    = __builtin_amdgcn_mfma_f32_16x16x32_bf16(af, *(const bf16x8*)(bn + k * 32), accN,    0, 0, 0);
      }
      int j = jt * 16 + ln;
      #pragma unroll
      for (int r = 0; r < 4; r++){
        float rv = sigmoidf_(aRZ0[q][r] + brz0[q]);
        float zv = sigmoidf_(aRZ1[q][r] + brz1[q]);
        float nv = tanhf_(accN[r] + bin_[q] + rv * (aN[q][r] + bhn_[q]));
        float hv = (1.f - zv) * nv + zv * hreg[q][r];
        hreg[q][r] = hv;
        h16[(lrow + r) * PAD + j] = f2b(hv);
      }
    }
    __syncthreads();

    // P1: gh (into aRZ/aN for next step), e_{s+1}, y_s
    p1_gh();
    {
      f32x4 acce[4] = {};
      const unsigned short* a0 = h16 + ln * PAD + kq * 8;
      #pragma unroll 2
      for (int k = 0; k < 16; ++k){
        bf16x8 af = *(const bf16x8*)(a0 + k * 32);
        #pragma unroll
        for (int q = 0; q < 4; q++){
          const unsigned short* bp = Wbig + (size_t)((w * 4 + q) * 16 + ln) * 512 + k * 32 + kq * 8;
          acce[q] = __builtin_amdgcn_mfma_f32_16x16x32_bf16(af, *(const bf16x8*)bp, acce[q], 0, 0, 0);
        }
      }
      #pragma unroll
      for (int q = 0; q < 4; q++){
        int j = (w * 4 + q) * 16 + ln;
        #pragma unroll
        for (int r = 0; r < 4; r++){
          float v = acce[q][r] + ebig[q];
          e16[(lrow + r) * PAD + j] = f2b(v > 0.f ? v : 0.f);
        }
      }
    }
    if (w < 4){
      f32x4 accy = {};
      const unsigned short* a0 = h16 + ln * PAD + kq * 8;
      const unsigned short* bp = Wbig + (size_t)(2048 + w * 16 + ln) * 512 + kq * 8;
      #pragma unroll 2
      for (int k = 0; k < 16; ++k){
        bf16x8 af = *(const bf16x8*)(a0 + k * 32);
        accy = __builtin_amdgcn_mfma_f32_16x16x32_bf16(af, *(const bf16x8*)(bp + k * 32), accy, 0, 0, 0);
      }
      #pragma unroll
      for (int r = 0; r < 4; r++){
        int b = g0 + lrow + r;
        out[((size_t)b * 280 + 140 + s) * 64 + w * 16 + ln] = accy[r] + yb;
      }
    }
    __syncthreads();
  }
}

extern "C" void kernel_launch(void* const* d_in, const int* in_sizes, int n_in,
                              void* d_out, int out_size, void* d_ws, size_t ws_size,
                              hipStream_t stream)
{
  const float* enc   = (const float*)d_in[0];
  const float* ehid  = (const float*)d_in[1];
  const float* embW  = (const float*)d_in[2];
  const float* emb_b = (const float*)d_in[3];
  const float* w_ih  = (const float*)d_in[4];
  const float* w_hh  = (const float*)d_in[5];
  const float* b_ih  = (const float*)d_in[6];
  const float* b_hh  = (const float*)d_in[7];
  const float* out_W = (const float*)d_in[8];
  const float* out_b = (const float*)d_in[9];
  const float* reg_W = (const float*)d_in[10];
  const float* reg_b = (const float*)d_in[11];
  float* out = (float*)d_out;

  char* ws = (char*)d_ws;
  size_t off = 0;
  auto alloc = [&](size_t bytes)->char*{
    char* p = ws + off; off += (bytes + 255) & ~(size_t)255; return p;
  };
  unsigned short* Wbig    = (unsigned short*)alloc((size_t)2112 * 512 * 2);
  unsigned short* wih16   = (unsigned short*)alloc((size_t)1536 * 512 * 2);
  unsigned short* embW16  = (unsigned short*)alloc((size_t)512 * 256 * 2);
  unsigned short* regW16  = (unsigned short*)alloc((size_t)64 * 256 * 2);
  unsigned short* outWT16 = (unsigned short*)alloc((size_t)512 * 256 * 2);
  float*          bias_big= (float*)alloc((size_t)2112 * 4);

  k_prep<<<7241, 256, 0, stream>>>(embW, emb_b, w_ih, w_hh, b_hh,
                                   out_W, out_b, reg_W, reg_b,
                                   wih16, Wbig, embW16, regW16, outWT16, bias_big);

  k_gemms<<<72, 256, 0, stream>>>(embW, reg_W, outWT16, Wbig);

  k_loop<<<256, 512, 0, stream>>>(enc, ehid, emb_b, b_ih, b_hh,
                                  wih16, Wbig, embW16, regW16,
                                  bias_big, reg_b, out);
}